// Round 1
// baseline (93.334 us; speedup 1.0000x reference)
//
#include <hip/hip_runtime.h>
#include <cstdint>
#include <cstddef>

// Problem constants (reference: N=8192, C=1000, A=768)
#define N_SAMPLES 8192
#define N_CLASSES 1000
#define C_PAD     1024
#define A_DIM     768
#define K_DIM     1536   // 2*A  (concatenated [u ; v] / [W^2 ; W])
#define BM 128
#define BN 128
#define BK 64

typedef __attribute__((ext_vector_type(8))) __bf16 bf16x8;
typedef __attribute__((ext_vector_type(4))) float  f32x4;

// ---------------- prep B: Wcat[c][a] = W[c,a]^2 ; Wcat[c][768+a] = W[c,a] ----
__global__ void prep_B(const float* __restrict__ W, __bf16* __restrict__ Wcat) {
    int c = blockIdx.x;
    int tid = threadIdx.x;
    if (c < N_CLASSES) {
        for (int a = tid; a < A_DIM; a += 256) {
            float w = W[(size_t)c * A_DIM + a];
            Wcat[(size_t)c * K_DIM + a]        = (__bf16)(w * w);
            Wcat[(size_t)c * K_DIM + A_DIM + a] = (__bf16)w;
        }
    } else {
        // zero padding rows so GEMM dot = 0 there
        for (int a = tid; a < K_DIM; a += 256)
            Wcat[(size_t)c * K_DIM + a] = (__bf16)0.0f;
    }
}

// ---------------- prep A: UV[n][a] = cv_k ; UV[n][768+a] = -2*Wk*cv_k ; t3 ---
__global__ void prep_A(const float* __restrict__ W, const float* __restrict__ CV,
                       const int* __restrict__ labels,
                       __bf16* __restrict__ UV, float* __restrict__ t3) {
    int n = blockIdx.x;
    int tid = threadIdx.x;
    int lab = labels[n];
    const float* wr = W + (size_t)lab * A_DIM;
    const float* cr = CV + (size_t)lab * A_DIM;
    float part = 0.f;
    for (int a = tid; a < A_DIM; a += 256) {
        float wk = wr[a];
        float cv = cr[a];
        UV[(size_t)n * K_DIM + a]         = (__bf16)cv;
        UV[(size_t)n * K_DIM + A_DIM + a] = (__bf16)(-2.0f * wk * cv);
        part += wk * wk * cv;   // t3 kept exact in fp32
    }
    #pragma unroll
    for (int s = 32; s > 0; s >>= 1) part += __shfl_xor(part, s);
    __shared__ float tmp[4];
    int lane = tid & 63, wv = tid >> 6;
    if (lane == 0) tmp[wv] = part;
    __syncthreads();
    if (tid == 0) t3[n] = tmp[0] + tmp[1] + tmp[2] + tmp[3];
}

// ---------------- GEMM: AUG[n][c] = logits + 0.5*ratio*(UV.Wcat^T + t3) ------
__global__ __launch_bounds__(256, 2) void gemm_aug(
        const __bf16* __restrict__ UV, const __bf16* __restrict__ Wcat,
        const float* __restrict__ logits, const float* __restrict__ t3,
        const float* __restrict__ ratiop, __bf16* __restrict__ AUG) {
    __shared__ __align__(16) __bf16 As[BM * BK];
    __shared__ __align__(16) __bf16 Bs[BN * BK];
    int tid  = threadIdx.x;
    int lane = tid & 63;
    int wave = tid >> 6;
    int bid  = blockIdx.x;
    int rowTile = bid >> 3;          // 64 row tiles of 128 samples
    int colTile = bid & 7;           // 8 col tiles of 128 classes
    int rowBase = rowTile * BM;
    int colBase = colTile * BN;
    int wr = wave >> 1;              // 2x2 wave grid, each wave owns 64x64
    int wc = wave & 1;

    f32x4 acc[4][4];
    #pragma unroll
    for (int m = 0; m < 4; ++m)
        #pragma unroll
        for (int n = 0; n < 4; ++n)
            acc[m][n] = (f32x4){0.f, 0.f, 0.f, 0.f};

    for (int kt = 0; kt < K_DIM / BK; ++kt) {
        int k0 = kt * BK;
        // stage both tiles: 128x64 bf16 = 16KB each, 16B/lane direct-to-LDS
        #pragma unroll
        for (int i = 0; i < 4; ++i) {
            int lin  = i * 256 + tid;      // chunk id 0..1023
            int row  = lin >> 3;           // tile row 0..127
            int cch  = lin & 7;            // 16B chunk in row (8 bf16)
            int base = i * 256 + (tid & ~63);   // wave-uniform chunk base
            const __bf16* ga = UV   + (size_t)(rowBase + row) * K_DIM + k0 + cch * 8;
            __builtin_amdgcn_global_load_lds(
                (const __attribute__((address_space(1))) void*)ga,
                (__attribute__((address_space(3))) void*)((char*)As + (size_t)base * 16),
                16, 0, 0);
            const __bf16* gb = Wcat + (size_t)(colBase + row) * K_DIM + k0 + cch * 8;
            __builtin_amdgcn_global_load_lds(
                (const __attribute__((address_space(1))) void*)gb,
                (__attribute__((address_space(3))) void*)((char*)Bs + (size_t)base * 16),
                16, 0, 0);
        }
        __syncthreads();   // drains vmcnt before any wave reads LDS
        #pragma unroll
        for (int kk = 0; kk < 2; ++kk) {
            int kof = kk * 32 + (lane >> 4) * 8;
            bf16x8 afrag[4], bfrag[4];
            #pragma unroll
            for (int m = 0; m < 4; ++m) {
                int r = wr * 64 + m * 16 + (lane & 15);
                afrag[m] = *reinterpret_cast<const bf16x8*>(&As[r * BK + kof]);
            }
            #pragma unroll
            for (int n = 0; n < 4; ++n) {
                int ccol = wc * 64 + n * 16 + (lane & 15);
                bfrag[n] = *reinterpret_cast<const bf16x8*>(&Bs[ccol * BK + kof]);
            }
            #pragma unroll
            for (int m = 0; m < 4; ++m)
                #pragma unroll
                for (int n = 0; n < 4; ++n)
                    acc[m][n] = __builtin_amdgcn_mfma_f32_16x16x32_bf16(
                        afrag[m], bfrag[n], acc[m][n], 0, 0, 0);
        }
        __syncthreads();   // protect LDS before next stage
    }

    // epilogue: C/D layout col=lane&15, row=(lane>>4)*4+j  [verified m89/m91]
    float h  = 0.5f * ratiop[0];
    int   lr = (lane >> 4) * 4;
    int   lc = lane & 15;
    #pragma unroll
    for (int m = 0; m < 4; ++m) {
        #pragma unroll
        for (int n = 0; n < 4; ++n) {
            int gr0 = rowBase + wr * 64 + m * 16 + lr;
            int gc  = colBase + wc * 64 + n * 16 + lc;
            #pragma unroll
            for (int j = 0; j < 4; ++j) {
                int r = gr0 + j;
                float v = h * (acc[m][n][j] + t3[r]);
                if (gc < N_CLASSES) v += logits[(size_t)r * N_CLASSES + gc];
                AUG[(size_t)r * C_PAD + gc] = (__bf16)v;
            }
        }
    }
}

// ---------------- per-row log-softmax NLL at label --------------------------
__global__ void softmax_loss(const __bf16* __restrict__ AUG,
                             const int* __restrict__ labels,
                             float* __restrict__ rowloss) {
    int n = blockIdx.x;
    int tid = threadIdx.x;
    __shared__ float row[N_CLASSES];
    __shared__ float tmp[4];
    __shared__ float smax;
    float lmax = -1e30f;
    for (int c = tid; c < N_CLASSES; c += 256) {
        float v = (float)AUG[(size_t)n * C_PAD + c];
        row[c] = v;
        lmax = fmaxf(lmax, v);
    }
    #pragma unroll
    for (int s = 32; s > 0; s >>= 1) lmax = fmaxf(lmax, __shfl_xor(lmax, s));
    int lane = tid & 63, wv = tid >> 6;
    if (lane == 0) tmp[wv] = lmax;
    __syncthreads();
    if (tid == 0) smax = fmaxf(fmaxf(tmp[0], tmp[1]), fmaxf(tmp[2], tmp[3]));
    __syncthreads();
    float m = smax;
    float part = 0.f;
    for (int c = tid; c < N_CLASSES; c += 256) part += __expf(row[c] - m);
    #pragma unroll
    for (int s = 32; s > 0; s >>= 1) part += __shfl_xor(part, s);
    __syncthreads();               // tmp reuse: all prior reads done
    if (lane == 0) tmp[wv] = part;
    __syncthreads();
    if (tid == 0) {
        float sum = tmp[0] + tmp[1] + tmp[2] + tmp[3];
        rowloss[n] = logf(sum) + m - row[labels[n]];
    }
}

// ---------------- deterministic final mean ----------------------------------
__global__ void finalize(const float* __restrict__ rowloss, float* __restrict__ out) {
    int tid = threadIdx.x;
    float part = 0.f;
    for (int i = tid; i < N_SAMPLES; i += 256) part += rowloss[i];
    #pragma unroll
    for (int s = 32; s > 0; s >>= 1) part += __shfl_xor(part, s);
    __shared__ float tmp[4];
    int lane = tid & 63, wv = tid >> 6;
    if (lane == 0) tmp[wv] = part;
    __syncthreads();
    if (tid == 0) out[0] = (tmp[0] + tmp[1] + tmp[2] + tmp[3]) / (float)N_SAMPLES;
}

extern "C" void kernel_launch(void* const* d_in, const int* in_sizes, int n_in,
                              void* d_out, int out_size, void* d_ws, size_t ws_size,
                              hipStream_t stream) {
    const float* W      = (const float*)d_in[0];   // fc_weight [C, A]
    // d_in[1] = features [N, A] — unused by the reference math
    const float* logits = (const float*)d_in[2];   // [N, C]
    const int*   labels = (const int*)d_in[3];     // [N]
    const float* ratio  = (const float*)d_in[4];   // scalar
    const float* CV     = (const float*)d_in[5];   // cv_matrix [C, A]
    // d_in[6] = manner — unused

    // workspace layout (bytes), total ~45.2 MB
    char* ws = (char*)d_ws;
    __bf16* Wcat   = (__bf16*)(ws + 0);            //  3,145,728 B  [1024][1536] bf16
    __bf16* UV     = (__bf16*)(ws + 3145728);      // 25,165,824 B  [8192][1536] bf16
    float*  t3     = (float*) (ws + 28311552);     //     32,768 B  [8192] f32
    __bf16* AUG    = (__bf16*)(ws + 28344320);     // 16,777,216 B  [8192][1024] bf16
    float*  rowloss= (float*) (ws + 45121536);     //     32,768 B  [8192] f32

    prep_B<<<C_PAD, 256, 0, stream>>>(W, Wcat);
    prep_A<<<N_SAMPLES, 256, 0, stream>>>(W, CV, labels, UV, t3);
    gemm_aug<<<512, 256, 0, stream>>>(UV, Wcat, logits, t3, ratio, AUG);
    softmax_loss<<<N_SAMPLES, 256, 0, stream>>>(AUG, labels, rowloss);
    finalize<<<1, 256, 0, stream>>>(rowloss, (float*)d_out);
}

// Round 2
// 74.189 us; speedup vs baseline: 1.2581x; 1.2581x over previous
//
#include <hip/hip_runtime.h>
#include <cstdint>
#include <cstddef>

// Problem constants (reference: N=8192, C=1000, A=768)
#define N_SAMPLES 8192
#define N_CLASSES 1000
#define C_PAD     1024
#define A_DIM     768
#define K_DIM     1536   // 2*A  (concatenated [u ; v] / [W^2 ; W])
#define BM 128
#define BN 128
#define BK 64
#define NT (K_DIM / BK)  // 24 K-steps

typedef __attribute__((ext_vector_type(8))) __bf16 bf16x8;
typedef __attribute__((ext_vector_type(4))) __bf16 bf16x4;
typedef __attribute__((ext_vector_type(4))) float  f32x4;

// ---------------- prep B: Wcat[c][a] = W[c,a]^2 ; Wcat[c][768+a] = W[c,a] ----
// one wave per (padded) class row; float4 in, bf16x4 out
__global__ void prep_B(const float* __restrict__ W, __bf16* __restrict__ Wcat) {
    int gw   = (blockIdx.x * blockDim.x + threadIdx.x) >> 6;
    int lane = threadIdx.x & 63;
    if (gw >= C_PAD) return;
    if (gw < N_CLASSES) {
        #pragma unroll
        for (int p = 0; p < 3; ++p) {                // 3*256 = 768
            int a = p * 256 + lane * 4;
            f32x4 w = *reinterpret_cast<const f32x4*>(W + (size_t)gw * A_DIM + a);
            bf16x4 sq, li;
            #pragma unroll
            for (int j = 0; j < 4; ++j) { sq[j] = (__bf16)(w[j] * w[j]); li[j] = (__bf16)w[j]; }
            *reinterpret_cast<bf16x4*>(Wcat + (size_t)gw * K_DIM + a)         = sq;
            *reinterpret_cast<bf16x4*>(Wcat + (size_t)gw * K_DIM + A_DIM + a) = li;
        }
    } else {
        bf16x4 z = {(__bf16)0.f, (__bf16)0.f, (__bf16)0.f, (__bf16)0.f};
        #pragma unroll
        for (int p = 0; p < 6; ++p)                  // 6*256 = 1536
            *reinterpret_cast<bf16x4*>(Wcat + (size_t)gw * K_DIM + p * 256 + lane * 4) = z;
    }
}

// ---------------- prep A: UV[n][a] = cv_k ; UV[n][768+a] = -2*Wk*cv_k ; t3 ---
// one wave per sample; float4 gathered reads (1000 distinct 3KB rows -> L2)
__global__ void prep_A(const float* __restrict__ W, const float* __restrict__ CV,
                       const int* __restrict__ labels,
                       __bf16* __restrict__ UV, float* __restrict__ t3) {
    int gw   = (blockIdx.x * blockDim.x + threadIdx.x) >> 6;
    int lane = threadIdx.x & 63;
    if (gw >= N_SAMPLES) return;
    int lab = labels[gw];
    const float* wr = W  + (size_t)lab * A_DIM;
    const float* cr = CV + (size_t)lab * A_DIM;
    float part = 0.f;
    #pragma unroll
    for (int p = 0; p < 3; ++p) {
        int a = p * 256 + lane * 4;
        f32x4 wk = *reinterpret_cast<const f32x4*>(wr + a);
        f32x4 cv = *reinterpret_cast<const f32x4*>(cr + a);
        bf16x4 u, v;
        #pragma unroll
        for (int j = 0; j < 4; ++j) {
            u[j] = (__bf16)cv[j];
            v[j] = (__bf16)(-2.0f * wk[j] * cv[j]);
            part += wk[j] * wk[j] * cv[j];           // t3 exact in fp32
        }
        *reinterpret_cast<bf16x4*>(UV + (size_t)gw * K_DIM + a)         = u;
        *reinterpret_cast<bf16x4*>(UV + (size_t)gw * K_DIM + A_DIM + a) = v;
    }
    #pragma unroll
    for (int s = 32; s > 0; s >>= 1) part += __shfl_xor(part, s);
    if (lane == 0) t3[gw] = part;
}

// ---------------- GEMM: AUG[n][c] = logits + 0.5*ratio*(UV.Wcat^T + t3) ------
// 128x128 tile, double-buffered LDS (prefetch-before-compute), XOR source-swizzle
__global__ __launch_bounds__(256, 2) void gemm_aug(
        const __bf16* __restrict__ UV, const __bf16* __restrict__ Wcat,
        const float* __restrict__ logits, const float* __restrict__ t3,
        const float* __restrict__ ratiop, __bf16* __restrict__ AUG) {
    __shared__ __align__(16) __bf16 As[2][BM * BK];   // 2 x 16 KB
    __shared__ __align__(16) __bf16 Bs[2][BN * BK];   // 2 x 16 KB
    int tid  = threadIdx.x;
    int lane = tid & 63;
    int wave = tid >> 6;
    int bid  = blockIdx.x;
    int rowTile = bid >> 3;          // 64 row tiles of 128 samples
    int colTile = bid & 7;           // 8 col tiles of 128 classes
    int rowBase = rowTile * BM;
    int colBase = colTile * BN;
    int wr = wave >> 1;              // 2x2 wave grid, each wave owns 64x64
    int wc = wave & 1;

    f32x4 acc[4][4];
    #pragma unroll
    for (int m = 0; m < 4; ++m)
        #pragma unroll
        for (int n = 0; n < 4; ++n)
            acc[m][n] = (f32x4){0.f, 0.f, 0.f, 0.f};

    // stage one 128x64 A-tile + 128x64 B-tile into buffer b.
    // LDS dest is LINEAR (global_load_lds writes base + lane*16);
    // the swizzle lives in the GLOBAL source chunk index: cch ^ (row&7).
    auto stage = [&](int b, int k0) {
        #pragma unroll
        for (int i = 0; i < 4; ++i) {
            int lin  = i * 256 + tid;            // LDS chunk id 0..1023
            int row  = lin >> 3;                 // tile row 0..127
            int scch = (lin & 7) ^ (row & 7);    // swizzled global 16B-chunk
            int base = i * 256 + (tid & ~63);    // wave-uniform chunk base
            const __bf16* ga = UV   + (size_t)(rowBase + row) * K_DIM + k0 + scch * 8;
            __builtin_amdgcn_global_load_lds(
                (const __attribute__((address_space(1))) void*)ga,
                (__attribute__((address_space(3))) void*)((char*)&As[b][0] + (size_t)base * 16),
                16, 0, 0);
            const __bf16* gb = Wcat + (size_t)(colBase + row) * K_DIM + k0 + scch * 8;
            __builtin_amdgcn_global_load_lds(
                (const __attribute__((address_space(1))) void*)gb,
                (__attribute__((address_space(3))) void*)((char*)&Bs[b][0] + (size_t)base * 16),
                16, 0, 0);
        }
    };

    int buf = 0;
    stage(0, 0);
    __syncthreads();                 // drain prologue loads
    for (int kt = 0; kt < NT; ++kt) {
        if (kt + 1 < NT) stage(buf ^ 1, (kt + 1) * BK);   // prefetch next tile
        #pragma unroll
        for (int kk = 0; kk < 2; ++kk) {
            // global chunk g = kk*4 + (lane>>4); stored at g ^ (row&7) = g ^ (lane&7)
            int swch = ((kk * 4 + (lane >> 4)) ^ (lane & 7)) * 8;
            bf16x8 afrag[4], bfrag[4];
            #pragma unroll
            for (int m = 0; m < 4; ++m) {
                int r = wr * 64 + m * 16 + (lane & 15);
                afrag[m] = *reinterpret_cast<const bf16x8*>(&As[buf][r * BK + swch]);
            }
            #pragma unroll
            for (int n = 0; n < 4; ++n) {
                int c = wc * 64 + n * 16 + (lane & 15);
                bfrag[n] = *reinterpret_cast<const bf16x8*>(&Bs[buf][c * BK + swch]);
            }
            #pragma unroll
            for (int m = 0; m < 4; ++m)
                #pragma unroll
                for (int n = 0; n < 4; ++n)
                    acc[m][n] = __builtin_amdgcn_mfma_f32_16x16x32_bf16(
                        afrag[m], bfrag[n], acc[m][n], 0, 0, 0);
        }
        __syncthreads();             // drains vmcnt (next tile ready) + lgkmcnt
        buf ^= 1;
    }

    // epilogue: C/D layout col=lane&15, row=(lane>>4)*4+j  [verified m89/m91]
    float h  = 0.5f * ratiop[0];
    int   lr = (lane >> 4) * 4;
    int   lc = lane & 15;
    #pragma unroll
    for (int m = 0; m < 4; ++m) {
        #pragma unroll
        for (int n = 0; n < 4; ++n) {
            int gr0 = rowBase + wr * 64 + m * 16 + lr;
            int gc  = colBase + wc * 64 + n * 16 + lc;
            #pragma unroll
            for (int j = 0; j < 4; ++j) {
                int r = gr0 + j;
                float v;
                if (gc < N_CLASSES)
                    v = h * (acc[m][n][j] + t3[r]) + logits[(size_t)r * N_CLASSES + gc];
                else
                    v = -1e30f;      // pad cols: exp(-1e30 - m) == 0 in softmax
                AUG[(size_t)r * C_PAD + gc] = (__bf16)v;
            }
        }
    }
}

// ---------------- per-row log-softmax NLL at label --------------------------
// one wave per row: 1024 bf16 = 16 per lane, all in registers
__global__ void softmax_loss(const __bf16* __restrict__ AUG,
                             const int* __restrict__ labels,
                             float* __restrict__ rowloss) {
    int gw   = (blockIdx.x * blockDim.x + threadIdx.x) >> 6;
    int lane = threadIdx.x & 63;
    if (gw >= N_SAMPLES) return;
    const __bf16* rowp = AUG + (size_t)gw * C_PAD;
    bf16x8 v0 = *reinterpret_cast<const bf16x8*>(rowp + lane * 8);
    bf16x8 v1 = *reinterpret_cast<const bf16x8*>(rowp + 512 + lane * 8);
    float f[16];
    #pragma unroll
    for (int j = 0; j < 8; ++j) { f[j] = (float)v0[j]; f[8 + j] = (float)v1[j]; }
    float m = -1e30f;
    #pragma unroll
    for (int j = 0; j < 16; ++j) m = fmaxf(m, f[j]);
    #pragma unroll
    for (int s = 32; s > 0; s >>= 1) m = fmaxf(m, __shfl_xor(m, s));
    float sum = 0.f;
    #pragma unroll
    for (int j = 0; j < 16; ++j) sum += __expf(f[j] - m);
    #pragma unroll
    for (int s = 32; s > 0; s >>= 1) sum += __shfl_xor(sum, s);
    if (lane == 0) {
        float tv = (float)rowp[labels[gw]];
        rowloss[gw] = logf(sum) + m - tv;
    }
}

// ---------------- deterministic final mean ----------------------------------
__global__ void finalize(const float* __restrict__ rowloss, float* __restrict__ out) {
    int tid = threadIdx.x;
    float part = 0.f;
    for (int i = tid; i < N_SAMPLES; i += 256) part += rowloss[i];
    #pragma unroll
    for (int s = 32; s > 0; s >>= 1) part += __shfl_xor(part, s);
    __shared__ float tmp[4];
    int lane = tid & 63, wv = tid >> 6;
    if (lane == 0) tmp[wv] = part;
    __syncthreads();
    if (tid == 0) out[0] = (tmp[0] + tmp[1] + tmp[2] + tmp[3]) / (float)N_SAMPLES;
}

extern "C" void kernel_launch(void* const* d_in, const int* in_sizes, int n_in,
                              void* d_out, int out_size, void* d_ws, size_t ws_size,
                              hipStream_t stream) {
    const float* W      = (const float*)d_in[0];   // fc_weight [C, A]
    // d_in[1] = features [N, A] — unused by the reference math
    const float* logits = (const float*)d_in[2];   // [N, C]
    const int*   labels = (const int*)d_in[3];     // [N]
    const float* ratio  = (const float*)d_in[4];   // scalar
    const float* CV     = (const float*)d_in[5];   // cv_matrix [C, A]
    // d_in[6] = manner — unused

    // workspace layout (bytes), total ~45.2 MB
    char* ws = (char*)d_ws;
    __bf16* Wcat    = (__bf16*)(ws + 0);            //  3,145,728 B  [1024][1536] bf16
    __bf16* UV      = (__bf16*)(ws + 3145728);      // 25,165,824 B  [8192][1536] bf16
    float*  t3      = (float*) (ws + 28311552);     //     32,768 B  [8192] f32
    __bf16* AUG     = (__bf16*)(ws + 28344320);     // 16,777,216 B  [8192][1024] bf16
    float*  rowloss = (float*) (ws + 45121536);     //     32,768 B  [8192] f32

    prep_B<<<C_PAD / 4, 256, 0, stream>>>(W, Wcat);
    prep_A<<<N_SAMPLES / 4, 256, 0, stream>>>(W, CV, labels, UV, t3);
    gemm_aug<<<512, 256, 0, stream>>>(UV, Wcat, logits, t3, ratio, AUG);
    softmax_loss<<<N_SAMPLES / 4, 256, 0, stream>>>(AUG, labels, rowloss);
    finalize<<<1, 256, 0, stream>>>(rowloss, (float*)d_out);
}

// Round 3
// 66.750 us; speedup vs baseline: 1.3983x; 1.1114x over previous
//
#include <hip/hip_runtime.h>
#include <cstdint>
#include <cstddef>

// Problem constants (reference: N=8192, C=1000, A=768)
#define N_SAMPLES 8192
#define N_CLASSES 1000
#define C_PAD     1024
#define A_DIM     768
#define K_DIM     1536   // 2*A  (concatenated [u ; v] / [W^2 ; W])
#define BM 256
#define BN 128
#define BK 64
#define NT (K_DIM / BK)  // 24 K-steps

typedef __attribute__((ext_vector_type(8))) __bf16 bf16x8;
typedef __attribute__((ext_vector_type(4))) __bf16 bf16x4;
typedef __attribute__((ext_vector_type(4))) float  f32x4;

#define WAIT_VM(N) do { asm volatile("s_waitcnt vmcnt(" #N ")" ::: "memory"); \
                        __builtin_amdgcn_sched_barrier(0); } while (0)
#define WAIT_LGKM0 do { asm volatile("s_waitcnt lgkmcnt(0)" ::: "memory"); \
                        __builtin_amdgcn_sched_barrier(0); } while (0)

// ---------------- prep B: Wcat[c][a] = W[c,a]^2 ; Wcat[c][768+a] = W[c,a] ----
__global__ void prep_B(const float* __restrict__ W, __bf16* __restrict__ Wcat) {
    int gw   = (blockIdx.x * blockDim.x + threadIdx.x) >> 6;
    int lane = threadIdx.x & 63;
    if (gw >= C_PAD) return;
    if (gw < N_CLASSES) {
        #pragma unroll
        for (int p = 0; p < 3; ++p) {                // 3*256 = 768
            int a = p * 256 + lane * 4;
            f32x4 w = *reinterpret_cast<const f32x4*>(W + (size_t)gw * A_DIM + a);
            bf16x4 sq, li;
            #pragma unroll
            for (int j = 0; j < 4; ++j) { sq[j] = (__bf16)(w[j] * w[j]); li[j] = (__bf16)w[j]; }
            *reinterpret_cast<bf16x4*>(Wcat + (size_t)gw * K_DIM + a)         = sq;
            *reinterpret_cast<bf16x4*>(Wcat + (size_t)gw * K_DIM + A_DIM + a) = li;
        }
    } else {
        bf16x4 z = {(__bf16)0.f, (__bf16)0.f, (__bf16)0.f, (__bf16)0.f};
        #pragma unroll
        for (int p = 0; p < 6; ++p)                  // 6*256 = 1536
            *reinterpret_cast<bf16x4*>(Wcat + (size_t)gw * K_DIM + p * 256 + lane * 4) = z;
    }
}

// ---------------- prep A: UV[n][a] = cv_k ; UV[n][768+a] = -2*Wk*cv_k ; t3 ---
__global__ void prep_A(const float* __restrict__ W, const float* __restrict__ CV,
                       const int* __restrict__ labels,
                       __bf16* __restrict__ UV, float* __restrict__ t3) {
    int gw   = (blockIdx.x * blockDim.x + threadIdx.x) >> 6;
    int lane = threadIdx.x & 63;
    if (gw >= N_SAMPLES) return;
    int lab = labels[gw];
    const float* wr = W  + (size_t)lab * A_DIM;
    const float* cr = CV + (size_t)lab * A_DIM;
    float part = 0.f;
    #pragma unroll
    for (int p = 0; p < 3; ++p) {
        int a = p * 256 + lane * 4;
        f32x4 wk = *reinterpret_cast<const f32x4*>(wr + a);
        f32x4 cv = *reinterpret_cast<const f32x4*>(cr + a);
        bf16x4 u, v;
        #pragma unroll
        for (int j = 0; j < 4; ++j) {
            u[j] = (__bf16)cv[j];
            v[j] = (__bf16)(-2.0f * wk[j] * cv[j]);
            part += wk[j] * wk[j] * cv[j];           // t3 exact in fp32
        }
        *reinterpret_cast<bf16x4*>(UV + (size_t)gw * K_DIM + a)         = u;
        *reinterpret_cast<bf16x4*>(UV + (size_t)gw * K_DIM + A_DIM + a) = v;
    }
    #pragma unroll
    for (int s = 32; s > 0; s >>= 1) part += __shfl_xor(part, s);
    if (lane == 0) t3[gw] = part;
}

// ---------------- GEMM: AUG[n][c] = logits + 0.5*ratio*(UV.Wcat^T + t3) ------
// 256x128 tile, 512 thr (8 waves, 4Mx2N), 3-stage LDS pipeline, counted vmcnt,
// XOR source-swizzle (conflict-free, verified R2), XCD-chunked block swizzle.
__global__ __launch_bounds__(512, 2) void gemm_aug(
        const __bf16* __restrict__ UV, const __bf16* __restrict__ Wcat,
        const float* __restrict__ logits, const float* __restrict__ t3,
        const float* __restrict__ ratiop, __bf16* __restrict__ AUG) {
    __shared__ __align__(16) __bf16 As[3][BM * BK];   // 3 x 32 KB
    __shared__ __align__(16) __bf16 Bs[3][BN * BK];   // 3 x 16 KB  (144 KB total)
    int tid  = threadIdx.x;
    int lane = tid & 63;
    int wave = tid >> 6;
    // XCD-chunked bijective swizzle: 256 blocks, 8 XCDs, 32 blocks/XCD.
    // Within an XCD: colTile varies fastest -> UV row-panel L2-resident.
    int wgid = (blockIdx.x & 7) * 32 + (blockIdx.x >> 3);
    int rowTile = wgid >> 3;         // 32 row tiles of 256 samples
    int colTile = wgid & 7;          // 8 col tiles of 128 classes
    int rowBase = rowTile * BM;
    int colBase = colTile * BN;
    int wr = wave >> 1;              // 4x2 wave grid, each wave owns 64x64
    int wc = wave & 1;

    f32x4 acc[4][4];
    #pragma unroll
    for (int m = 0; m < 4; ++m)
        #pragma unroll
        for (int n = 0; n < 4; ++n)
            acc[m][n] = (f32x4){0.f, 0.f, 0.f, 0.f};

    // stage one 256x64 A-tile + 128x64 B-tile into buffer b (6 loads/thread).
    // LDS dest LINEAR (global_load_lds = wave-uniform base + lane*16);
    // swizzle lives in the GLOBAL source chunk index: cch ^ (row&7).
    auto stage = [&](int b, int k0) {
        #pragma unroll
        for (int i = 0; i < 4; ++i) {            // A: 2048 chunks
            int lin  = i * 512 + tid;
            int row  = lin >> 3;                 // 0..255
            int scch = (lin & 7) ^ (row & 7);
            int base = i * 512 + (tid & ~63);
            const __bf16* ga = UV + (size_t)(rowBase + row) * K_DIM + k0 + scch * 8;
            __builtin_amdgcn_global_load_lds(
                (const __attribute__((address_space(1))) void*)ga,
                (__attribute__((address_space(3))) void*)((char*)&As[b][0] + (size_t)base * 16),
                16, 0, 0);
        }
        #pragma unroll
        for (int i = 0; i < 2; ++i) {            // B: 1024 chunks
            int lin  = i * 512 + tid;
            int row  = lin >> 3;                 // 0..127
            int scch = (lin & 7) ^ (row & 7);
            int base = i * 512 + (tid & ~63);
            const __bf16* gb = Wcat + (size_t)(colBase + row) * K_DIM + k0 + scch * 8;
            __builtin_amdgcn_global_load_lds(
                (const __attribute__((address_space(1))) void*)gb,
                (__attribute__((address_space(3))) void*)((char*)&Bs[b][0] + (size_t)base * 16),
                16, 0, 0);
        }
    };

    auto compute = [&](int b) {
        #pragma unroll
        for (int kk = 0; kk < 2; ++kk) {
            // global chunk g = kk*4 + (lane>>4); stored at g ^ (row&7) = g ^ (lane&7)
            int swch = ((kk * 4 + (lane >> 4)) ^ (lane & 7)) * 8;
            bf16x8 afrag[4], bfrag[4];
            #pragma unroll
            for (int m = 0; m < 4; ++m) {
                int r = wr * 64 + m * 16 + (lane & 15);
                afrag[m] = *reinterpret_cast<const bf16x8*>(&As[b][r * BK + swch]);
            }
            #pragma unroll
            for (int n = 0; n < 4; ++n) {
                int c = wc * 64 + n * 16 + (lane & 15);
                bfrag[n] = *reinterpret_cast<const bf16x8*>(&Bs[b][c * BK + swch]);
            }
            #pragma unroll
            for (int m = 0; m < 4; ++m)
                #pragma unroll
                for (int n = 0; n < 4; ++n)
                    acc[m][n] = __builtin_amdgcn_mfma_f32_16x16x32_bf16(
                        afrag[m], bfrag[n], acc[m][n], 0, 0, 0);
        }
    };

    // Pipeline: depth-2 prefetch, vmcnt counted (6 loads/thread/tile):
    // steady state leaves tiles k+1,k+2 in flight -> vmcnt(12).
    stage(0, 0);
    stage(1, BK);
    for (int kt = 0; kt < NT; ++kt) {
        if (kt + 2 < NT) stage((kt + 2) % 3, (kt + 2) * BK);
        if      (kt < NT - 2) WAIT_VM(12);
        else if (kt == NT - 2) WAIT_VM(6);
        else                   WAIT_VM(0);
        __builtin_amdgcn_s_barrier();        // all waves' tile-kt loads landed
        compute(kt % 3);
        WAIT_LGKM0;                          // my ds_reads retired (WAR safety)
        __builtin_amdgcn_s_barrier();        // buffer kt%3 free for overwrite
    }

    // epilogue: C/D layout col=lane&15, row=(lane>>4)*4+j  [verified m89/m91]
    float h  = 0.5f * ratiop[0];
    int   lr = (lane >> 4) * 4;
    int   lc = lane & 15;
    #pragma unroll
    for (int m = 0; m < 4; ++m) {
        #pragma unroll
        for (int n = 0; n < 4; ++n) {
            int gr0 = rowBase + wr * 64 + m * 16 + lr;
            int gc  = colBase + wc * 64 + n * 16 + lc;
            #pragma unroll
            for (int j = 0; j < 4; ++j) {
                int r = gr0 + j;
                float v;
                if (gc < N_CLASSES)
                    v = h * (acc[m][n][j] + t3[r]) + logits[(size_t)r * N_CLASSES + gc];
                else
                    v = -1e30f;      // pad cols vanish in softmax
                AUG[(size_t)r * C_PAD + gc] = (__bf16)v;
            }
        }
    }
}

// ---------------- per-row log-softmax NLL at label --------------------------
// one wave per row: 1024 bf16 = 16 per lane, all in registers
__global__ void softmax_loss(const __bf16* __restrict__ AUG,
                             const int* __restrict__ labels,
                             float* __restrict__ rowloss) {
    int gw   = (blockIdx.x * blockDim.x + threadIdx.x) >> 6;
    int lane = threadIdx.x & 63;
    if (gw >= N_SAMPLES) return;
    const __bf16* rowp = AUG + (size_t)gw * C_PAD;
    bf16x8 v0 = *reinterpret_cast<const bf16x8*>(rowp + lane * 8);
    bf16x8 v1 = *reinterpret_cast<const bf16x8*>(rowp + 512 + lane * 8);
    float f[16];
    #pragma unroll
    for (int j = 0; j < 8; ++j) { f[j] = (float)v0[j]; f[8 + j] = (float)v1[j]; }
    float m = -1e30f;
    #pragma unroll
    for (int j = 0; j < 16; ++j) m = fmaxf(m, f[j]);
    #pragma unroll
    for (int s = 32; s > 0; s >>= 1) m = fmaxf(m, __shfl_xor(m, s));
    float sum = 0.f;
    #pragma unroll
    for (int j = 0; j < 16; ++j) sum += __expf(f[j] - m);
    #pragma unroll
    for (int s = 32; s > 0; s >>= 1) sum += __shfl_xor(sum, s);
    if (lane == 0) {
        float tv = (float)rowp[labels[gw]];
        rowloss[gw] = logf(sum) + m - tv;
    }
}

// ---------------- deterministic final mean ----------------------------------
__global__ void finalize(const float* __restrict__ rowloss, float* __restrict__ out) {
    int tid = threadIdx.x;
    float part = 0.f;
    #pragma unroll
    for (int i = 0; i < 8; ++i) part += rowloss[i * 1024 + tid];
    #pragma unroll
    for (int s = 32; s > 0; s >>= 1) part += __shfl_xor(part, s);
    __shared__ float tmp[16];
    int lane = tid & 63, wv = tid >> 6;
    if (lane == 0) tmp[wv] = part;
    __syncthreads();
    if (tid == 0) {
        float sum = 0.f;
        #pragma unroll
        for (int w = 0; w < 16; ++w) sum += tmp[w];
        out[0] = sum / (float)N_SAMPLES;
    }
}

extern "C" void kernel_launch(void* const* d_in, const int* in_sizes, int n_in,
                              void* d_out, int out_size, void* d_ws, size_t ws_size,
                              hipStream_t stream) {
    const float* W      = (const float*)d_in[0];   // fc_weight [C, A]
    // d_in[1] = features [N, A] — unused by the reference math
    const float* logits = (const float*)d_in[2];   // [N, C]
    const int*   labels = (const int*)d_in[3];     // [N]
    const float* ratio  = (const float*)d_in[4];   // scalar
    const float* CV     = (const float*)d_in[5];   // cv_matrix [C, A]
    // d_in[6] = manner — unused

    // workspace layout (bytes), total ~45.2 MB
    char* ws = (char*)d_ws;
    __bf16* Wcat    = (__bf16*)(ws + 0);            //  3,145,728 B  [1024][1536] bf16
    __bf16* UV      = (__bf16*)(ws + 3145728);      // 25,165,824 B  [8192][1536] bf16
    float*  t3      = (float*) (ws + 28311552);     //     32,768 B  [8192] f32
    __bf16* AUG     = (__bf16*)(ws + 28344320);     // 16,777,216 B  [8192][1024] bf16
    float*  rowloss = (float*) (ws + 45121536);     //     32,768 B  [8192] f32

    prep_B<<<C_PAD / 4, 256, 0, stream>>>(W, Wcat);
    prep_A<<<N_SAMPLES / 4, 256, 0, stream>>>(W, CV, labels, UV, t3);
    gemm_aug<<<256, 512, 0, stream>>>(UV, Wcat, logits, t3, ratio, AUG);
    softmax_loss<<<N_SAMPLES / 4, 256, 0, stream>>>(AUG, labels, rowloss);
    finalize<<<1, 1024, 0, stream>>>(rowloss, (float*)d_out);
}